// Round 3
// baseline (937.067 us; speedup 1.0000x reference)
//
#include <hip/hip_runtime.h>
#include <stdint.h>

#define NN 50000   // N_NODES (fixed in reference)

typedef unsigned short u16;
typedef __attribute__((ext_vector_type(8))) short short8;   // 8 x bf16 fragment
typedef __attribute__((ext_vector_type(4))) float f32x4;

__device__ __forceinline__ u16 f2b(float f){
  union { float f; uint32_t i; } v; v.f = f;
  uint32_t r = (v.i + 0x7FFFu + ((v.i >> 16) & 1u)) >> 16;   // RNE
  return (u16)r;
}

// ---------------- CSR build (dst-sorted adjacency incl. self-loops) ----------------

__global__ void count_k(const int* __restrict__ dst, int* __restrict__ cnt, int E){
  int i = blockIdx.x * 256 + threadIdx.x;
  int tot = E + NN;
  if (i >= tot) return;
  int d = (i < E) ? dst[i] : (i - E);        // self-loop edges appended
  atomicAdd(&cnt[d], 1);
}

__global__ __launch_bounds__(1024) void scan_k(const int* __restrict__ cnt,
                                               int* __restrict__ row_ptr,
                                               int* __restrict__ cursor){
  __shared__ int lds[1024];
  const int CH = (NN + 1023) / 1024;         // 49
  int tid = threadIdx.x;
  int base = tid * CH;
  int sum = 0;
  for (int i = 0; i < CH; i++){ int idx = base + i; if (idx < NN) sum += cnt[idx]; }
  lds[tid] = sum; __syncthreads();
  for (int off = 1; off < 1024; off <<= 1){
    int v = (tid >= off) ? lds[tid - off] : 0;
    __syncthreads();
    lds[tid] += v;
    __syncthreads();
  }
  int run = (tid > 0) ? lds[tid - 1] : 0;    // exclusive prefix of this chunk
  for (int i = 0; i < CH; i++){
    int idx = base + i;
    if (idx < NN){ int c = cnt[idx]; row_ptr[idx] = run; cursor[idx] = run; run += c; }
  }
  if (tid == 1023) row_ptr[NN] = run;
}

__global__ void scatter_k(const int* __restrict__ src, const int* __restrict__ dst,
                          int* __restrict__ cursor, int* __restrict__ csr, int E){
  int i = blockIdx.x * 256 + threadIdx.x;
  int tot = E + NN;
  if (i >= tot) return;
  int s, d;
  if (i < E){ s = src[i]; d = dst[i]; } else { s = i - E; d = i - E; }
  int pos = atomicAdd(&cursor[d], 1);
  csr[pos] = s;
}

// -------- W transpose+convert: fp32 [K,N] -> bf16 [N,K] (GEMM B-frags contiguous) ---

__global__ void transpose_k(const float* __restrict__ W, u16* __restrict__ Wt, int K, int N){
  int i = blockIdx.x * 256 + threadIdx.x;
  if (i >= K * N) return;
  int n = i / K, k = i - n * K;
  Wt[i] = f2b(W[k * N + n]);                 // write coalesced
}

// ------- bf16 MFMA GEMM: C[M,N](fp32) = A[M,K] * B[K,N]; Bt bf16 [N,K]; A fp32|bf16 -

template<bool A_FP32>
__global__ __launch_bounds__(256) void gemm_k(const void* __restrict__ Aptr,
                                              const u16* __restrict__ Bt,
                                              float* __restrict__ C,
                                              int M, int N, int K){
  __shared__ u16 As[64 * 40];                // 64 rows x 32 k, padded 40 (2-way conflicts free)
  __shared__ u16 Bs[64 * 40];
  const int tid  = threadIdx.x;
  const int wave = tid >> 6, lane = tid & 63;
  const int quad = lane >> 4, l16 = lane & 15;
  const int m0 = blockIdx.x * 64, n0 = blockIdx.y * 64;
  const int srow = tid >> 2;                 // staging: 64 rows x (4 threads x 8 elems)
  const int scol = (tid & 3) * 8;

  f32x4 acc[4] = {};

  for (int k0 = 0; k0 < K; k0 += 32){
    short8 va = {0,0,0,0,0,0,0,0};
    int gm = m0 + srow;
    if (gm < M){
      if (A_FP32){
        const float* A = (const float*)Aptr;
        const f32x4 f0 = *(const f32x4*)(A + (size_t)gm * K + k0 + scol);
        const f32x4 f1 = *(const f32x4*)(A + (size_t)gm * K + k0 + scol + 4);
        va[0] = (short)f2b(f0.x); va[1] = (short)f2b(f0.y);
        va[2] = (short)f2b(f0.z); va[3] = (short)f2b(f0.w);
        va[4] = (short)f2b(f1.x); va[5] = (short)f2b(f1.y);
        va[6] = (short)f2b(f1.z); va[7] = (short)f2b(f1.w);
      } else {
        va = *(const short8*)((const u16*)Aptr + (size_t)gm * K + k0 + scol);
      }
    }
    *(short8*)(&As[srow * 40 + scol]) = va;

    short8 vb = {0,0,0,0,0,0,0,0};
    int gn = n0 + srow;
    if (gn < N) vb = *(const short8*)(Bt + (size_t)gn * K + k0 + scol);
    *(short8*)(&Bs[srow * 40 + scol]) = vb;

    __syncthreads();
    short8 af = *(const short8*)(&As[(wave * 16 + l16) * 40 + quad * 8]);
#pragma unroll
    for (int i = 0; i < 4; i++){
      short8 bf = *(const short8*)(&Bs[(i * 16 + l16) * 40 + quad * 8]);
      acc[i] = __builtin_amdgcn_mfma_f32_16x16x32_bf16(af, bf, acc[i], 0, 0, 0);
    }
    __syncthreads();
  }

#pragma unroll
  for (int i = 0; i < 4; i++){
    int n = n0 + i * 16 + l16;
#pragma unroll
    for (int r = 0; r < 4; r++){
      int m = m0 + wave * 16 + quad * 4 + r; // C/D: col=lane&15, row=quad*4+reg
      if (m < M && n < N) C[(size_t)m * N + n] = acc[i][r];
    }
  }
}

// ---------------- attention coefficients (h fp32, att vectors fp32) ----------------

// H=4, C=64: one wave per node; lane owns channels 4l..4l+3 (head = l>>4)
__global__ __launch_bounds__(256) void attn4_k(const float* __restrict__ h,
                                               const float* __restrict__ atts,
                                               const float* __restrict__ attd,
                                               float* __restrict__ a_s,
                                               float* __restrict__ a_d){
  int w = blockIdx.x * 4 + (threadIdx.x >> 6);
  if (w >= NN) return;
  int lane = threadIdx.x & 63;
  const float* hp = h + (size_t)w * 256 + lane * 4;
  float ps = 0.f, pd = 0.f;
#pragma unroll
  for (int k = 0; k < 4; k++){
    float hv = hp[k];
    ps += hv * atts[lane * 4 + k];
    pd += hv * attd[lane * 4 + k];
  }
#pragma unroll
  for (int off = 8; off >= 1; off >>= 1){    // reduce within 16-lane head group
    ps += __shfl_xor(ps, off);
    pd += __shfl_xor(pd, off);
  }
  if ((lane & 15) == 0){
    a_s[w * 4 + (lane >> 4)] = ps;
    a_d[w * 4 + (lane >> 4)] = pd;
  }
}

// H=1, C=40
__global__ __launch_bounds__(256) void attn1_k(const float* __restrict__ h,
                                               const float* __restrict__ atts,
                                               const float* __restrict__ attd,
                                               float* __restrict__ a_s,
                                               float* __restrict__ a_d){
  int w = blockIdx.x * 4 + (threadIdx.x >> 6);
  if (w >= NN) return;
  int lane = threadIdx.x & 63;
  float ps = 0.f, pd = 0.f;
  if (lane < 40){
    float hv = h[(size_t)w * 40 + lane];
    ps = hv * atts[lane];
    pd = hv * attd[lane];
  }
#pragma unroll
  for (int off = 32; off >= 1; off >>= 1){
    ps += __shfl_xor(ps, off);
    pd += __shfl_xor(pd, off);
  }
  if (lane == 0){ a_s[w] = ps; a_d[w] = pd; }
}

// ---------------- edge softmax + aggregate (gather per dst node, no atomics) -------

// H=4, C=64 -> out[N,256] = ELU(softmax-agg + bias), bf16 out (feeds next GEMM)
__global__ __launch_bounds__(256) void agg4_k(const float* __restrict__ h,
                                              const float* __restrict__ a_s,
                                              const float* __restrict__ a_d,
                                              const int* __restrict__ row_ptr,
                                              const int* __restrict__ csr,
                                              const float* __restrict__ bias,
                                              u16* __restrict__ out){
  int w = blockIdx.x * 4 + (threadIdx.x >> 6);
  if (w >= NN) return;
  int lane = threadIdx.x & 63;
  int head = lane >> 4;
  float ad = a_d[w * 4 + head];
  int beg = row_ptr[w], end = row_ptr[w + 1];

  float m = -1e30f;
  for (int j = beg; j < end; j++){
    int s = csr[j];
    float e = a_s[s * 4 + head] + ad;
    e = e > 0.f ? e : 0.2f * e;
    m = fmaxf(m, e);
  }
  float denom = 0.f, acc0 = 0.f, acc1 = 0.f, acc2 = 0.f, acc3 = 0.f;
  for (int j = beg; j < end; j++){
    int s = csr[j];
    float e = a_s[s * 4 + head] + ad;
    e = e > 0.f ? e : 0.2f * e;
    float al = __expf(e - m);
    denom += al;                             // redundantly consistent within head group
    const f32x4 hv = *(const f32x4*)(h + (size_t)s * 256 + lane * 4);
    acc0 += al * hv.x;
    acc1 += al * hv.y;
    acc2 += al * hv.z;
    acc3 += al * hv.w;
  }
  float inv = 1.f / fmaxf(denom, 1e-30f);    // >=1 edge guaranteed (self-loop)
  float o0 = acc0 * inv + bias[lane * 4 + 0];
  float o1 = acc1 * inv + bias[lane * 4 + 1];
  float o2 = acc2 * inv + bias[lane * 4 + 2];
  float o3 = acc3 * inv + bias[lane * 4 + 3];
  o0 = o0 > 0.f ? o0 : __expf(o0) - 1.f;     // ELU
  o1 = o1 > 0.f ? o1 : __expf(o1) - 1.f;
  o2 = o2 > 0.f ? o2 : __expf(o2) - 1.f;
  o3 = o3 > 0.f ? o3 : __expf(o3) - 1.f;
  ushort4 r; r.x = f2b(o0); r.y = f2b(o1); r.z = f2b(o2); r.w = f2b(o3);
  *(ushort4*)(out + (size_t)w * 256 + lane * 4) = r;
}

// H=1, C=40 -> out[N,40] (no ELU), final layer, fp32 out -> d_out
__global__ __launch_bounds__(256) void agg1_k(const float* __restrict__ h,
                                              const float* __restrict__ a_s,
                                              const float* __restrict__ a_d,
                                              const int* __restrict__ row_ptr,
                                              const int* __restrict__ csr,
                                              const float* __restrict__ bias,
                                              float* __restrict__ out){
  int w = blockIdx.x * 4 + (threadIdx.x >> 6);
  if (w >= NN) return;
  int lane = threadIdx.x & 63;
  float ad = a_d[w];
  int beg = row_ptr[w], end = row_ptr[w + 1];

  float m = -1e30f;
  for (int j = beg; j < end; j++){
    int s = csr[j];
    float e = a_s[s] + ad;
    e = e > 0.f ? e : 0.2f * e;
    m = fmaxf(m, e);
  }
  float denom = 0.f, acc = 0.f;
  for (int j = beg; j < end; j++){
    int s = csr[j];
    float e = a_s[s] + ad;
    e = e > 0.f ? e : 0.2f * e;
    float al = __expf(e - m);
    denom += al;
    if (lane < 40) acc += al * h[(size_t)s * 40 + lane];
  }
  if (lane < 40){
    float o = acc / fmaxf(denom, 1e-30f) + bias[lane];
    out[(size_t)w * 40 + lane] = o;
  }
}

// ---------------- driver -----------------------------------------------------------

extern "C" void kernel_launch(void* const* d_in, const int* in_sizes, int n_in,
                              void* d_out, int out_size, void* d_ws, size_t ws_size,
                              hipStream_t stream){
  const float* x   = (const float*)d_in[0];
  const int*   ei  = (const int*)d_in[1];
  const float* W1  = (const float*)d_in[2];
  const float* as1 = (const float*)d_in[3];
  const float* ad1 = (const float*)d_in[4];
  const float* b1  = (const float*)d_in[5];
  const float* W2  = (const float*)d_in[6];
  const float* as2 = (const float*)d_in[7];
  const float* ad2 = (const float*)d_in[8];
  const float* b2  = (const float*)d_in[9];
  const float* W3  = (const float*)d_in[10];
  const float* as3 = (const float*)d_in[11];
  const float* ad3 = (const float*)d_in[12];
  const float* b3  = (const float*)d_in[13];

  const int E = in_sizes[1] / 2;             // 800000
  const int ETOT = E + NN;
  const int* src_arr = ei;
  const int* dst_arr = ei + E;

  char* ws = (char*)d_ws;
  size_t off = 0;
  auto alloc = [&](size_t bytes) -> void* {
    void* p = ws + off; off += (bytes + 255) & ~(size_t)255; return p;
  };
  int*   cnt     = (int*)  alloc((size_t)NN * 4);
  int*   row_ptr = (int*)  alloc((size_t)(NN + 1) * 4);
  int*   cursor  = (int*)  alloc((size_t)NN * 4);
  int*   csr     = (int*)  alloc((size_t)ETOT * 4);
  u16*   W1t     = (u16*)  alloc((size_t)512 * 256 * 2);
  u16*   W2t     = (u16*)  alloc((size_t)256 * 256 * 2);
  u16*   W3t     = (u16*)  alloc((size_t)256 * 40 * 2);
  float* a_s     = (float*)alloc((size_t)NN * 4 * 4);
  float* a_d     = (float*)alloc((size_t)NN * 4 * 4);
  float* hbuf    = (float*)alloc((size_t)NN * 256 * 4);   // fp32 h
  u16*   xbuf    = (u16*)  alloc((size_t)NN * 256 * 2);   // bf16 inter-layer activations
  (void)ws_size; (void)n_in; (void)out_size;

  // CSR build (same graph reused by all 3 layers)
  hipMemsetAsync(cnt, 0, (size_t)NN * 4, stream);
  int egrid = (ETOT + 255) / 256;
  count_k  <<<egrid, 256, 0, stream>>>(dst_arr, cnt, E);
  scan_k   <<<1, 1024, 0, stream>>>(cnt, row_ptr, cursor);
  scatter_k<<<egrid, 256, 0, stream>>>(src_arr, dst_arr, cursor, csr, E);

  // weight transposes (fp32 -> bf16)
  transpose_k<<<(512 * 256 + 255) / 256, 256, 0, stream>>>(W1, W1t, 512, 256);
  transpose_k<<<(256 * 256 + 255) / 256, 256, 0, stream>>>(W2, W2t, 256, 256);
  transpose_k<<<(256 * 40  + 255) / 256, 256, 0, stream>>>(W3, W3t, 256, 40);

  dim3 blk(256);
  dim3 gA((NN + 63) / 64, 4);                // M x N/64 for N=256
  dim3 gC((NN + 63) / 64, 1);                // N=40
  int nodeblocks = (NN + 3) / 4;             // 12500, one wave per node

  // Layer 1: A = x (fp32), K=512
  gemm_k<true> <<<gA, blk, 0, stream>>>(x, W1t, hbuf, NN, 256, 512);
  attn4_k<<<nodeblocks, blk, 0, stream>>>(hbuf, as1, ad1, a_s, a_d);
  agg4_k <<<nodeblocks, blk, 0, stream>>>(hbuf, a_s, a_d, row_ptr, csr, b1, xbuf);

  // Layer 2: A = xbuf (bf16), K=256
  gemm_k<false><<<gA, blk, 0, stream>>>(xbuf, W2t, hbuf, NN, 256, 256);
  attn4_k<<<nodeblocks, blk, 0, stream>>>(hbuf, as2, ad2, a_s, a_d);
  agg4_k <<<nodeblocks, blk, 0, stream>>>(hbuf, a_s, a_d, row_ptr, csr, b2, xbuf);

  // Layer 3 (H=1, C=40) -> d_out (fp32)
  gemm_k<false><<<gC, blk, 0, stream>>>(xbuf, W3t, hbuf, NN, 40, 256);
  attn1_k<<<nodeblocks, blk, 0, stream>>>(hbuf, as3, ad3, a_s, a_d);
  agg1_k <<<nodeblocks, blk, 0, stream>>>(hbuf, a_s, a_d, row_ptr, csr, b3, (float*)d_out);
}

// Round 4
// 810.427 us; speedup vs baseline: 1.1563x; 1.1563x over previous
//
#include <hip/hip_runtime.h>
#include <stdint.h>

#define NN 50000   // N_NODES (fixed in reference)

typedef unsigned short u16;
typedef __attribute__((ext_vector_type(8))) short short8;   // 8 x bf16 fragment
typedef __attribute__((ext_vector_type(4))) float f32x4;

__device__ __forceinline__ u16 f2b(float f){
  union { float f; uint32_t i; } v; v.f = f;
  uint32_t r = (v.i + 0x7FFFu + ((v.i >> 16) & 1u)) >> 16;   // RNE
  return (u16)r;
}

// ---------------- CSR build (dst-sorted adjacency incl. self-loops) ----------------

__global__ void count_k(const int* __restrict__ dst, int* __restrict__ cnt, int E){
  int i = blockIdx.x * 256 + threadIdx.x;
  int tot = E + NN;
  if (i >= tot) return;
  int d = (i < E) ? dst[i] : (i - E);        // self-loop edges appended
  atomicAdd(&cnt[d], 1);
}

__global__ __launch_bounds__(1024) void scan_k(const int* __restrict__ cnt,
                                               int* __restrict__ row_ptr,
                                               int* __restrict__ cursor){
  __shared__ int lds[1024];
  const int CH = (NN + 1023) / 1024;         // 49
  int tid = threadIdx.x;
  int base = tid * CH;
  int sum = 0;
  for (int i = 0; i < CH; i++){ int idx = base + i; if (idx < NN) sum += cnt[idx]; }
  lds[tid] = sum; __syncthreads();
  for (int off = 1; off < 1024; off <<= 1){
    int v = (tid >= off) ? lds[tid - off] : 0;
    __syncthreads();
    lds[tid] += v;
    __syncthreads();
  }
  int run = (tid > 0) ? lds[tid - 1] : 0;    // exclusive prefix of this chunk
  for (int i = 0; i < CH; i++){
    int idx = base + i;
    if (idx < NN){ int c = cnt[idx]; row_ptr[idx] = run; cursor[idx] = run; run += c; }
  }
  if (tid == 1023) row_ptr[NN] = run;
}

__global__ void scatter_k(const int* __restrict__ src, const int* __restrict__ dst,
                          int* __restrict__ cursor, int* __restrict__ csr, int E){
  int i = blockIdx.x * 256 + threadIdx.x;
  int tot = E + NN;
  if (i >= tot) return;
  int s, d;
  if (i < E){ s = src[i]; d = dst[i]; } else { s = i - E; d = i - E; }
  int pos = atomicAdd(&cursor[d], 1);
  csr[pos] = s;
}

// -------- W transpose+convert: fp32 [K,N] -> bf16 [N,K] (GEMM B-frags contiguous) ---

__global__ void transpose_k(const float* __restrict__ W, u16* __restrict__ Wt, int K, int N){
  int i = blockIdx.x * 256 + threadIdx.x;
  if (i >= K * N) return;
  int n = i / K, k = i - n * K;
  Wt[i] = f2b(W[k * N + n]);                 // write coalesced
}

// ---- wide GEMM: C[M,256](fp32) = A[M,K] * B[K,256]; Bt bf16 [256,K]; A fp32|bf16 ---
// 64x256 block tile: A fetched ONCE (grid-y=1), 4 waves x 16 rows x 16 n-tiles.

template<bool A_FP32>
__global__ __launch_bounds__(256) void gemm_wide_k(const void* __restrict__ Aptr,
                                                   const u16* __restrict__ Bt,
                                                   float* __restrict__ C,
                                                   int M, int K){
  __shared__ u16 As[64 * 40];                // stride 40 u16 = 80 B: 2-way conflicts (free)
  __shared__ u16 Bs[256 * 40];
  const int tid  = threadIdx.x;
  const int wave = tid >> 6, lane = tid & 63;
  const int quad = lane >> 4, l16 = lane & 15;
  const int m0 = blockIdx.x * 64;
  const int srow = tid >> 2;                 // 64 rows x (4 threads x 8 elems)
  const int scol = (tid & 3) * 8;

  f32x4 acc[16] = {};

  for (int k0 = 0; k0 < K; k0 += 32){
    // stage A (64 x 32)
    short8 va = {0,0,0,0,0,0,0,0};
    int gm = m0 + srow;
    if (gm < M){
      if (A_FP32){
        const float* A = (const float*)Aptr;
        const f32x4 f0 = *(const f32x4*)(A + (size_t)gm * K + k0 + scol);
        const f32x4 f1 = *(const f32x4*)(A + (size_t)gm * K + k0 + scol + 4);
        va[0] = (short)f2b(f0.x); va[1] = (short)f2b(f0.y);
        va[2] = (short)f2b(f0.z); va[3] = (short)f2b(f0.w);
        va[4] = (short)f2b(f1.x); va[5] = (short)f2b(f1.y);
        va[6] = (short)f2b(f1.z); va[7] = (short)f2b(f1.w);
      } else {
        va = *(const short8*)((const u16*)Aptr + (size_t)gm * K + k0 + scol);
      }
    }
    *(short8*)(&As[srow * 40 + scol]) = va;

    // stage B (256 x 32), same (row, 8-col) pattern -> 2-way conflicts only
#pragma unroll
    for (int rep = 0; rep < 4; rep++){
      int row = srow + 64 * rep;
      short8 vb = *(const short8*)(Bt + (size_t)row * K + k0 + scol);
      *(short8*)(&Bs[row * 40 + scol]) = vb;
    }

    __syncthreads();
    short8 af = *(const short8*)(&As[(wave * 16 + l16) * 40 + quad * 8]);
#pragma unroll
    for (int i = 0; i < 16; i++){
      short8 bf = *(const short8*)(&Bs[(i * 16 + l16) * 40 + quad * 8]);
      acc[i] = __builtin_amdgcn_mfma_f32_16x16x32_bf16(af, bf, acc[i], 0, 0, 0);
    }
    __syncthreads();
  }

#pragma unroll
  for (int i = 0; i < 16; i++){
    int n = i * 16 + l16;
#pragma unroll
    for (int r = 0; r < 4; r++){
      int mm = m0 + wave * 16 + quad * 4 + r; // C/D: col=lane&15, row=quad*4+reg
      if (mm < M) C[(size_t)mm * 256 + n] = acc[i][r];
    }
  }
}

// ---- narrow GEMM (layer 3): C[M,N] = A[M,K]*B[K,N], 64x64 tile, A bf16 ------------

__global__ __launch_bounds__(256) void gemm_k(const u16* __restrict__ A,
                                              const u16* __restrict__ Bt,
                                              float* __restrict__ C,
                                              int M, int N, int K){
  __shared__ u16 As[64 * 40];
  __shared__ u16 Bs[64 * 40];
  const int tid  = threadIdx.x;
  const int wave = tid >> 6, lane = tid & 63;
  const int quad = lane >> 4, l16 = lane & 15;
  const int m0 = blockIdx.x * 64, n0 = blockIdx.y * 64;
  const int srow = tid >> 2;
  const int scol = (tid & 3) * 8;

  f32x4 acc[4] = {};

  for (int k0 = 0; k0 < K; k0 += 32){
    short8 va = {0,0,0,0,0,0,0,0};
    int gm = m0 + srow;
    if (gm < M) va = *(const short8*)(A + (size_t)gm * K + k0 + scol);
    *(short8*)(&As[srow * 40 + scol]) = va;

    short8 vb = {0,0,0,0,0,0,0,0};
    int gn = n0 + srow;
    if (gn < N) vb = *(const short8*)(Bt + (size_t)gn * K + k0 + scol);
    *(short8*)(&Bs[srow * 40 + scol]) = vb;

    __syncthreads();
    short8 af = *(const short8*)(&As[(wave * 16 + l16) * 40 + quad * 8]);
#pragma unroll
    for (int i = 0; i < 4; i++){
      short8 bf = *(const short8*)(&Bs[(i * 16 + l16) * 40 + quad * 8]);
      acc[i] = __builtin_amdgcn_mfma_f32_16x16x32_bf16(af, bf, acc[i], 0, 0, 0);
    }
    __syncthreads();
  }

#pragma unroll
  for (int i = 0; i < 4; i++){
    int n = n0 + i * 16 + l16;
#pragma unroll
    for (int r = 0; r < 4; r++){
      int m = m0 + wave * 16 + quad * 4 + r;
      if (m < M && n < N) C[(size_t)m * N + n] = acc[i][r];
    }
  }
}

// ---------------- attention coefficients (h fp32, att vectors fp32) ----------------

// H=4, C=64: one wave per node; lane owns channels 4l..4l+3 (head = l>>4)
__global__ __launch_bounds__(256) void attn4_k(const float* __restrict__ h,
                                               const float* __restrict__ atts,
                                               const float* __restrict__ attd,
                                               float* __restrict__ a_s,
                                               float* __restrict__ a_d){
  int w = blockIdx.x * 4 + (threadIdx.x >> 6);
  if (w >= NN) return;
  int lane = threadIdx.x & 63;
  const f32x4 hv = *(const f32x4*)(h + (size_t)w * 256 + lane * 4);
  const f32x4 sv = *(const f32x4*)(atts + lane * 4);
  const f32x4 dv = *(const f32x4*)(attd + lane * 4);
  float ps = hv.x * sv.x + hv.y * sv.y + hv.z * sv.z + hv.w * sv.w;
  float pd = hv.x * dv.x + hv.y * dv.y + hv.z * dv.z + hv.w * dv.w;
#pragma unroll
  for (int off = 8; off >= 1; off >>= 1){    // reduce within 16-lane head group
    ps += __shfl_xor(ps, off);
    pd += __shfl_xor(pd, off);
  }
  if ((lane & 15) == 0){
    a_s[w * 4 + (lane >> 4)] = ps;
    a_d[w * 4 + (lane >> 4)] = pd;
  }
}

// H=1, C=40
__global__ __launch_bounds__(256) void attn1_k(const float* __restrict__ h,
                                               const float* __restrict__ atts,
                                               const float* __restrict__ attd,
                                               float* __restrict__ a_s,
                                               float* __restrict__ a_d){
  int w = blockIdx.x * 4 + (threadIdx.x >> 6);
  if (w >= NN) return;
  int lane = threadIdx.x & 63;
  float ps = 0.f, pd = 0.f;
  if (lane < 40){
    float hv = h[(size_t)w * 40 + lane];
    ps = hv * atts[lane];
    pd = hv * attd[lane];
  }
#pragma unroll
  for (int off = 32; off >= 1; off >>= 1){
    ps += __shfl_xor(ps, off);
    pd += __shfl_xor(pd, off);
  }
  if (lane == 0){ a_s[w] = ps; a_d[w] = pd; }
}

// -------- edge softmax + aggregate: ONLINE softmax, single pass, prefetched --------

// H=4, C=64 -> out[N,256] = ELU(softmax-agg + bias), bf16 out (feeds next GEMM)
__global__ __launch_bounds__(256) void agg4_k(const float* __restrict__ h,
                                              const float* __restrict__ a_s,
                                              const float* __restrict__ a_d,
                                              const int* __restrict__ row_ptr,
                                              const int* __restrict__ csr,
                                              const float* __restrict__ bias,
                                              u16* __restrict__ out){
  int w = blockIdx.x * 4 + (threadIdx.x >> 6);
  if (w >= NN) return;
  int lane = threadIdx.x & 63;
  int head = lane >> 4;
  float ad = a_d[w * 4 + head];
  int beg = row_ptr[w], end = row_ptr[w + 1];

  float m = -1e30f, denom = 0.f;
  float acc0 = 0.f, acc1 = 0.f, acc2 = 0.f, acc3 = 0.f;

  int s = csr[beg];
  float asv = a_s[s * 4 + head];
  f32x4 hv = *(const f32x4*)(h + (size_t)s * 256 + lane * 4);

  for (int j = beg; j < end; j++){
    // prefetch next edge's operands (overlaps with current compute)
    int jn = (j + 1 < end) ? j + 1 : j;
    int sn = csr[jn];
    float asn = a_s[sn * 4 + head];
    f32x4 hn = *(const f32x4*)(h + (size_t)sn * 256 + lane * 4);

    float e = asv + ad;
    e = e > 0.f ? e : 0.2f * e;
    float mn = fmaxf(m, e);
    float cold = __expf(m - mn);             // first iter: exp(-1e30) = 0
    float al = __expf(e - mn);
    denom = denom * cold + al;
    acc0 = acc0 * cold + al * hv.x;
    acc1 = acc1 * cold + al * hv.y;
    acc2 = acc2 * cold + al * hv.z;
    acc3 = acc3 * cold + al * hv.w;
    m = mn;
    asv = asn; hv = hn;
  }

  float inv = 1.f / fmaxf(denom, 1e-30f);    // >=1 edge guaranteed (self-loop)
  float o0 = acc0 * inv + bias[lane * 4 + 0];
  float o1 = acc1 * inv + bias[lane * 4 + 1];
  float o2 = acc2 * inv + bias[lane * 4 + 2];
  float o3 = acc3 * inv + bias[lane * 4 + 3];
  o0 = o0 > 0.f ? o0 : __expf(o0) - 1.f;     // ELU
  o1 = o1 > 0.f ? o1 : __expf(o1) - 1.f;
  o2 = o2 > 0.f ? o2 : __expf(o2) - 1.f;
  o3 = o3 > 0.f ? o3 : __expf(o3) - 1.f;
  ushort4 r; r.x = f2b(o0); r.y = f2b(o1); r.z = f2b(o2); r.w = f2b(o3);
  *(ushort4*)(out + (size_t)w * 256 + lane * 4) = r;
}

// H=1, C=40 -> out[N,40] (no ELU), final layer, fp32 out -> d_out
__global__ __launch_bounds__(256) void agg1_k(const float* __restrict__ h,
                                              const float* __restrict__ a_s,
                                              const float* __restrict__ a_d,
                                              const int* __restrict__ row_ptr,
                                              const int* __restrict__ csr,
                                              const float* __restrict__ bias,
                                              float* __restrict__ out){
  int w = blockIdx.x * 4 + (threadIdx.x >> 6);
  if (w >= NN) return;
  int lane = threadIdx.x & 63;
  float ad = a_d[w];
  int beg = row_ptr[w], end = row_ptr[w + 1];

  float m = -1e30f, denom = 0.f, acc = 0.f;
  int s = csr[beg];
  float asv = a_s[s];
  float hvv = h[(size_t)s * 40 + (lane < 40 ? lane : 0)];   // hbuf is big; safe

  for (int j = beg; j < end; j++){
    int jn = (j + 1 < end) ? j + 1 : j;
    int sn = csr[jn];
    float asn = a_s[sn];
    float hn = h[(size_t)sn * 40 + (lane < 40 ? lane : 0)];

    float e = asv + ad;
    e = e > 0.f ? e : 0.2f * e;
    float mn = fmaxf(m, e);
    float cold = __expf(m - mn);
    float al = __expf(e - mn);
    denom = denom * cold + al;
    acc = acc * cold + al * hvv;
    m = mn;
    asv = asn; hvv = hn;
  }

  if (lane < 40){
    float o = acc / fmaxf(denom, 1e-30f) + bias[lane];
    out[(size_t)w * 40 + lane] = o;
  }
}

// ---------------- driver -----------------------------------------------------------

extern "C" void kernel_launch(void* const* d_in, const int* in_sizes, int n_in,
                              void* d_out, int out_size, void* d_ws, size_t ws_size,
                              hipStream_t stream){
  const float* x   = (const float*)d_in[0];
  const int*   ei  = (const int*)d_in[1];
  const float* W1  = (const float*)d_in[2];
  const float* as1 = (const float*)d_in[3];
  const float* ad1 = (const float*)d_in[4];
  const float* b1  = (const float*)d_in[5];
  const float* W2  = (const float*)d_in[6];
  const float* as2 = (const float*)d_in[7];
  const float* ad2 = (const float*)d_in[8];
  const float* b2  = (const float*)d_in[9];
  const float* W3  = (const float*)d_in[10];
  const float* as3 = (const float*)d_in[11];
  const float* ad3 = (const float*)d_in[12];
  const float* b3  = (const float*)d_in[13];

  const int E = in_sizes[1] / 2;             // 800000
  const int ETOT = E + NN;
  const int* src_arr = ei;
  const int* dst_arr = ei + E;

  char* ws = (char*)d_ws;
  size_t off = 0;
  auto alloc = [&](size_t bytes) -> void* {
    void* p = ws + off; off += (bytes + 255) & ~(size_t)255; return p;
  };
  int*   cnt     = (int*)  alloc((size_t)NN * 4);
  int*   row_ptr = (int*)  alloc((size_t)(NN + 1) * 4);
  int*   cursor  = (int*)  alloc((size_t)NN * 4);
  int*   csr     = (int*)  alloc((size_t)ETOT * 4);
  u16*   W1t     = (u16*)  alloc((size_t)512 * 256 * 2);
  u16*   W2t     = (u16*)  alloc((size_t)256 * 256 * 2);
  u16*   W3t     = (u16*)  alloc((size_t)256 * 40 * 2);
  float* a_s     = (float*)alloc((size_t)NN * 4 * 4);
  float* a_d     = (float*)alloc((size_t)NN * 4 * 4);
  float* hbuf    = (float*)alloc((size_t)NN * 256 * 4);   // fp32 h
  u16*   xbuf    = (u16*)  alloc((size_t)NN * 256 * 2);   // bf16 inter-layer activations
  (void)ws_size; (void)n_in; (void)out_size;

  // CSR build (same graph reused by all 3 layers)
  hipMemsetAsync(cnt, 0, (size_t)NN * 4, stream);
  int egrid = (ETOT + 255) / 256;
  count_k  <<<egrid, 256, 0, stream>>>(dst_arr, cnt, E);
  scan_k   <<<1, 1024, 0, stream>>>(cnt, row_ptr, cursor);
  scatter_k<<<egrid, 256, 0, stream>>>(src_arr, dst_arr, cursor, csr, E);

  // weight transposes (fp32 -> bf16)
  transpose_k<<<(512 * 256 + 255) / 256, 256, 0, stream>>>(W1, W1t, 512, 256);
  transpose_k<<<(256 * 256 + 255) / 256, 256, 0, stream>>>(W2, W2t, 256, 256);
  transpose_k<<<(256 * 40  + 255) / 256, 256, 0, stream>>>(W3, W3t, 256, 40);

  dim3 blk(256);
  dim3 gW((NN + 63) / 64);                   // wide GEMM: full N=256 per block
  dim3 gC((NN + 63) / 64, 1);                // narrow GEMM layer 3 (N=40)
  int nodeblocks = (NN + 3) / 4;             // 12500, one wave per node

  // Layer 1: A = x (fp32), K=512
  gemm_wide_k<true> <<<gW, blk, 0, stream>>>(x, W1t, hbuf, NN, 512);
  attn4_k<<<nodeblocks, blk, 0, stream>>>(hbuf, as1, ad1, a_s, a_d);
  agg4_k <<<nodeblocks, blk, 0, stream>>>(hbuf, a_s, a_d, row_ptr, csr, b1, xbuf);

  // Layer 2: A = xbuf (bf16), K=256
  gemm_wide_k<false><<<gW, blk, 0, stream>>>(xbuf, W2t, hbuf, NN, 256);
  attn4_k<<<nodeblocks, blk, 0, stream>>>(hbuf, as2, ad2, a_s, a_d);
  agg4_k <<<nodeblocks, blk, 0, stream>>>(hbuf, a_s, a_d, row_ptr, csr, b2, xbuf);

  // Layer 3 (H=1, C=40) -> d_out (fp32)
  gemm_k<<<gC, blk, 0, stream>>>(xbuf, W3t, hbuf, NN, 40, 256);
  attn1_k<<<nodeblocks, blk, 0, stream>>>(hbuf, as3, ad3, a_s, a_d);
  agg1_k <<<nodeblocks, blk, 0, stream>>>(hbuf, a_s, a_d, row_ptr, csr, b3, (float*)d_out);
}

// Round 5
// 705.804 us; speedup vs baseline: 1.3277x; 1.1482x over previous
//
#include <hip/hip_runtime.h>
#include <stdint.h>

#define NN 50000   // N_NODES (fixed in reference)

typedef unsigned short u16;
typedef _Float16 f16;
typedef __attribute__((ext_vector_type(8))) _Float16 half8;   // MFMA A/B fragment (4 VGPRs)
typedef __attribute__((ext_vector_type(4))) _Float16 half4;
typedef __attribute__((ext_vector_type(4))) float f32x4;

// ---------------- CSR build (dst-sorted adjacency incl. self-loops) ----------------

__global__ void count_k(const int* __restrict__ dst, int* __restrict__ cnt, int E){
  int i = blockIdx.x * 256 + threadIdx.x;
  int tot = E + NN;
  if (i >= tot) return;
  int d = (i < E) ? dst[i] : (i - E);        // self-loop edges appended
  atomicAdd(&cnt[d], 1);
}

__global__ __launch_bounds__(1024) void scan_k(const int* __restrict__ cnt,
                                               int* __restrict__ row_ptr,
                                               int* __restrict__ cursor){
  __shared__ int lds[1024];
  const int CH = (NN + 1023) / 1024;         // 49
  int tid = threadIdx.x;
  int base = tid * CH;
  int sum = 0;
  for (int i = 0; i < CH; i++){ int idx = base + i; if (idx < NN) sum += cnt[idx]; }
  lds[tid] = sum; __syncthreads();
  for (int off = 1; off < 1024; off <<= 1){
    int v = (tid >= off) ? lds[tid - off] : 0;
    __syncthreads();
    lds[tid] += v;
    __syncthreads();
  }
  int run = (tid > 0) ? lds[tid - 1] : 0;    // exclusive prefix of this chunk
  for (int i = 0; i < CH; i++){
    int idx = base + i;
    if (idx < NN){ int c = cnt[idx]; row_ptr[idx] = run; cursor[idx] = run; run += c; }
  }
  if (tid == 1023) row_ptr[NN] = run;
}

__global__ void scatter_k(const int* __restrict__ src, const int* __restrict__ dst,
                          int* __restrict__ cursor, int* __restrict__ csr, int E){
  int i = blockIdx.x * 256 + threadIdx.x;
  int tot = E + NN;
  if (i >= tot) return;
  int s, d;
  if (i < E){ s = src[i]; d = dst[i]; } else { s = i - E; d = i - E; }
  int pos = atomicAdd(&cursor[d], 1);
  csr[pos] = s;
}

// -------- W transpose+convert: fp32 [K,N] -> fp16 [N,K] (GEMM B-frags contiguous) ---

__global__ void transpose_k(const float* __restrict__ W, f16* __restrict__ Wt, int K, int N){
  int i = blockIdx.x * 256 + threadIdx.x;
  if (i >= K * N) return;
  int n = i / K, k = i - n * K;
  Wt[i] = (f16)W[k * N + n];                 // write coalesced
}

// ---- wide GEMM: C[M,256](fp16) = A[M,K] * B[K,256]; Bt fp16 [256,K]; A fp32|fp16 ---
// 64x256 block tile: A fetched ONCE (grid-y=1), 4 waves x 16 rows x 16 n-tiles.

template<bool A_FP32>
__global__ __launch_bounds__(256) void gemm_wide_k(const void* __restrict__ Aptr,
                                                   const f16* __restrict__ Bt,
                                                   f16* __restrict__ C,
                                                   int M, int K){
  __shared__ f16 As[64 * 40];                // stride 40 f16 = 80 B: 2-way conflicts (free)
  __shared__ f16 Bs[256 * 40];
  const int tid  = threadIdx.x;
  const int wave = tid >> 6, lane = tid & 63;
  const int quad = lane >> 4, l16 = lane & 15;
  const int m0 = blockIdx.x * 64;
  const int srow = tid >> 2;                 // 64 rows x (4 threads x 8 elems)
  const int scol = (tid & 3) * 8;

  f32x4 acc[16] = {};

  for (int k0 = 0; k0 < K; k0 += 32){
    // stage A (64 x 32)
    half8 va = {0,0,0,0,0,0,0,0};
    int gm = m0 + srow;
    if (gm < M){
      if (A_FP32){
        const float* A = (const float*)Aptr;
        const f32x4 f0 = *(const f32x4*)(A + (size_t)gm * K + k0 + scol);
        const f32x4 f1 = *(const f32x4*)(A + (size_t)gm * K + k0 + scol + 4);
        va[0] = (f16)f0.x; va[1] = (f16)f0.y; va[2] = (f16)f0.z; va[3] = (f16)f0.w;
        va[4] = (f16)f1.x; va[5] = (f16)f1.y; va[6] = (f16)f1.z; va[7] = (f16)f1.w;
      } else {
        va = *(const half8*)((const f16*)Aptr + (size_t)gm * K + k0 + scol);
      }
    }
    *(half8*)(&As[srow * 40 + scol]) = va;

    // stage B (256 x 32), same (row, 8-col) pattern -> 2-way conflicts only
#pragma unroll
    for (int rep = 0; rep < 4; rep++){
      int row = srow + 64 * rep;
      half8 vb = *(const half8*)(Bt + (size_t)row * K + k0 + scol);
      *(half8*)(&Bs[row * 40 + scol]) = vb;
    }

    __syncthreads();
    half8 af = *(const half8*)(&As[(wave * 16 + l16) * 40 + quad * 8]);
#pragma unroll
    for (int i = 0; i < 16; i++){
      half8 bf = *(const half8*)(&Bs[(i * 16 + l16) * 40 + quad * 8]);
      acc[i] = __builtin_amdgcn_mfma_f32_16x16x32_f16(af, bf, acc[i], 0, 0, 0);
    }
    __syncthreads();
  }

#pragma unroll
  for (int i = 0; i < 16; i++){
    int n = i * 16 + l16;
#pragma unroll
    for (int r = 0; r < 4; r++){
      int mm = m0 + wave * 16 + quad * 4 + r; // C/D: col=lane&15, row=quad*4+reg
      if (mm < M) C[(size_t)mm * 256 + n] = (f16)acc[i][r];
    }
  }
}

// ---- narrow GEMM (layer 3): C[M,N](fp16) = A[M,K]*B[K,N], 64x64 tile, A fp16 ------

__global__ __launch_bounds__(256) void gemm_k(const f16* __restrict__ A,
                                              const f16* __restrict__ Bt,
                                              f16* __restrict__ C,
                                              int M, int N, int K){
  __shared__ f16 As[64 * 40];
  __shared__ f16 Bs[64 * 40];
  const int tid  = threadIdx.x;
  const int wave = tid >> 6, lane = tid & 63;
  const int quad = lane >> 4, l16 = lane & 15;
  const int m0 = blockIdx.x * 64, n0 = blockIdx.y * 64;
  const int srow = tid >> 2;
  const int scol = (tid & 3) * 8;

  f32x4 acc[4] = {};

  for (int k0 = 0; k0 < K; k0 += 32){
    half8 va = {0,0,0,0,0,0,0,0};
    int gm = m0 + srow;
    if (gm < M) va = *(const half8*)(A + (size_t)gm * K + k0 + scol);
    *(half8*)(&As[srow * 40 + scol]) = va;

    half8 vb = {0,0,0,0,0,0,0,0};
    int gn = n0 + srow;
    if (gn < N) vb = *(const half8*)(Bt + (size_t)gn * K + k0 + scol);
    *(half8*)(&Bs[srow * 40 + scol]) = vb;

    __syncthreads();
    half8 af = *(const half8*)(&As[(wave * 16 + l16) * 40 + quad * 8]);
#pragma unroll
    for (int i = 0; i < 4; i++){
      half8 bf = *(const half8*)(&Bs[(i * 16 + l16) * 40 + quad * 8]);
      acc[i] = __builtin_amdgcn_mfma_f32_16x16x32_f16(af, bf, acc[i], 0, 0, 0);
    }
    __syncthreads();
  }

#pragma unroll
  for (int i = 0; i < 4; i++){
    int n = n0 + i * 16 + l16;
#pragma unroll
    for (int r = 0; r < 4; r++){
      int m = m0 + wave * 16 + quad * 4 + r;
      if (m < M && n < N) C[(size_t)m * N + n] = (f16)acc[i][r];
    }
  }
}

// ---------------- attention coefficients (h fp16, att vectors fp32) ----------------

// H=4, C=64: one wave per node; lane owns channels 4l..4l+3 (head = l>>4)
__global__ __launch_bounds__(256) void attn4_k(const f16* __restrict__ h,
                                               const float* __restrict__ atts,
                                               const float* __restrict__ attd,
                                               float* __restrict__ a_s,
                                               float* __restrict__ a_d){
  int w = blockIdx.x * 4 + (threadIdx.x >> 6);
  if (w >= NN) return;
  int lane = threadIdx.x & 63;
  const half4 hv = *(const half4*)(h + (size_t)w * 256 + lane * 4);
  const f32x4 sv = *(const f32x4*)(atts + lane * 4);
  const f32x4 dv = *(const f32x4*)(attd + lane * 4);
  float h0 = (float)hv.x, h1 = (float)hv.y, h2 = (float)hv.z, h3 = (float)hv.w;
  float ps = h0 * sv.x + h1 * sv.y + h2 * sv.z + h3 * sv.w;
  float pd = h0 * dv.x + h1 * dv.y + h2 * dv.z + h3 * dv.w;
#pragma unroll
  for (int off = 8; off >= 1; off >>= 1){    // reduce within 16-lane head group
    ps += __shfl_xor(ps, off);
    pd += __shfl_xor(pd, off);
  }
  if ((lane & 15) == 0){
    a_s[w * 4 + (lane >> 4)] = ps;
    a_d[w * 4 + (lane >> 4)] = pd;
  }
}

// H=1, C=40
__global__ __launch_bounds__(256) void attn1_k(const f16* __restrict__ h,
                                               const float* __restrict__ atts,
                                               const float* __restrict__ attd,
                                               float* __restrict__ a_s,
                                               float* __restrict__ a_d){
  int w = blockIdx.x * 4 + (threadIdx.x >> 6);
  if (w >= NN) return;
  int lane = threadIdx.x & 63;
  float ps = 0.f, pd = 0.f;
  if (lane < 40){
    float hv = (float)h[(size_t)w * 40 + lane];
    ps = hv * atts[lane];
    pd = hv * attd[lane];
  }
#pragma unroll
  for (int off = 32; off >= 1; off >>= 1){
    ps += __shfl_xor(ps, off);
    pd += __shfl_xor(pd, off);
  }
  if (lane == 0){ a_s[w] = ps; a_d[w] = pd; }
}

// ---- edge softmax + aggregate: PAIRWISE online softmax, 2-deep prefetch -----------

__device__ __forceinline__ float lrelu(float e){ return e > 0.f ? e : 0.2f * e; }

// H=4, C=64 -> out[N,256](fp16) = ELU(softmax-agg + bias), feeds next GEMM
__global__ __launch_bounds__(256) void agg4_k(const f16* __restrict__ h,
                                              const float* __restrict__ a_s,
                                              const float* __restrict__ a_d,
                                              const int* __restrict__ row_ptr,
                                              const int* __restrict__ csr,
                                              const float* __restrict__ bias,
                                              f16* __restrict__ out){
  int w = blockIdx.x * 4 + (threadIdx.x >> 6);
  if (w >= NN) return;
  int lane = threadIdx.x & 63;
  int head = lane >> 4;
  float ad = a_d[w * 4 + head];
  int beg = row_ptr[w], end = row_ptr[w + 1];

  float m = -1e30f, denom = 0.f;
  float acc0 = 0.f, acc1 = 0.f, acc2 = 0.f, acc3 = 0.f;

  // preload first pair (clamped)
  int s0 = csr[beg];
  int s1 = csr[(beg + 1 < end) ? beg + 1 : beg];
  float e0 = a_s[s0 * 4 + head];
  float e1 = a_s[s1 * 4 + head];
  half4 h0 = *(const half4*)(h + (size_t)s0 * 256 + lane * 4);
  half4 h1 = *(const half4*)(h + (size_t)s1 * 256 + lane * 4);

  for (int j = beg; j < end; j += 2){
    // prefetch next pair (clamped to already-covered indices at the tail)
    int t0 = (j + 2 < end) ? j + 2 : j;
    int t1 = (j + 3 < end) ? j + 3 : j;
    int sp0 = csr[t0], sp1 = csr[t1];
    float ep0 = a_s[sp0 * 4 + head];
    float ep1 = a_s[sp1 * 4 + head];
    half4 hp0 = *(const half4*)(h + (size_t)sp0 * 256 + lane * 4);
    half4 hp1 = *(const half4*)(h + (size_t)sp1 * 256 + lane * 4);

    float ee0 = lrelu(e0 + ad);
    float ee1 = (j + 1 < end) ? lrelu(e1 + ad) : -1e30f;   // mask odd tail
    float mn = fmaxf(m, fmaxf(ee0, ee1));
    float cold = __expf(m - mn);                            // first iter: 0
    float al0 = __expf(ee0 - mn);
    float al1 = __expf(ee1 - mn);                           // masked -> 0
    denom = denom * cold + al0 + al1;
    acc0 = acc0 * cold + al0 * (float)h0.x + al1 * (float)h1.x;
    acc1 = acc1 * cold + al0 * (float)h0.y + al1 * (float)h1.y;
    acc2 = acc2 * cold + al0 * (float)h0.z + al1 * (float)h1.z;
    acc3 = acc3 * cold + al0 * (float)h0.w + al1 * (float)h1.w;
    m = mn;
    e0 = ep0; e1 = ep1; h0 = hp0; h1 = hp1;
  }

  float inv = 1.f / fmaxf(denom, 1e-30f);    // >=1 edge guaranteed (self-loop)
  float o0 = acc0 * inv + bias[lane * 4 + 0];
  float o1 = acc1 * inv + bias[lane * 4 + 1];
  float o2 = acc2 * inv + bias[lane * 4 + 2];
  float o3 = acc3 * inv + bias[lane * 4 + 3];
  o0 = o0 > 0.f ? o0 : __expf(o0) - 1.f;     // ELU
  o1 = o1 > 0.f ? o1 : __expf(o1) - 1.f;
  o2 = o2 > 0.f ? o2 : __expf(o2) - 1.f;
  o3 = o3 > 0.f ? o3 : __expf(o3) - 1.f;
  half4 r; r.x = (f16)o0; r.y = (f16)o1; r.z = (f16)o2; r.w = (f16)o3;
  *(half4*)(out + (size_t)w * 256 + lane * 4) = r;
}

// H=1, C=40 -> out[N,40](fp32) -> d_out, no ELU
__global__ __launch_bounds__(256) void agg1_k(const f16* __restrict__ h,
                                              const float* __restrict__ a_s,
                                              const float* __restrict__ a_d,
                                              const int* __restrict__ row_ptr,
                                              const int* __restrict__ csr,
                                              const float* __restrict__ bias,
                                              float* __restrict__ out){
  int w = blockIdx.x * 4 + (threadIdx.x >> 6);
  if (w >= NN) return;
  int lane = threadIdx.x & 63;
  int cl = (lane < 40) ? lane : 0;
  float ad = a_d[w];
  int beg = row_ptr[w], end = row_ptr[w + 1];

  float m = -1e30f, denom = 0.f, acc = 0.f;

  int s0 = csr[beg];
  int s1 = csr[(beg + 1 < end) ? beg + 1 : beg];
  float e0 = a_s[s0];
  float e1 = a_s[s1];
  float h0 = (float)h[(size_t)s0 * 40 + cl];
  float h1 = (float)h[(size_t)s1 * 40 + cl];

  for (int j = beg; j < end; j += 2){
    int t0 = (j + 2 < end) ? j + 2 : j;
    int t1 = (j + 3 < end) ? j + 3 : j;
    int sp0 = csr[t0], sp1 = csr[t1];
    float ep0 = a_s[sp0];
    float ep1 = a_s[sp1];
    float hp0 = (float)h[(size_t)sp0 * 40 + cl];
    float hp1 = (float)h[(size_t)sp1 * 40 + cl];

    float ee0 = lrelu(e0 + ad);
    float ee1 = (j + 1 < end) ? lrelu(e1 + ad) : -1e30f;
    float mn = fmaxf(m, fmaxf(ee0, ee1));
    float cold = __expf(m - mn);
    float al0 = __expf(ee0 - mn);
    float al1 = __expf(ee1 - mn);
    denom = denom * cold + al0 + al1;
    acc = acc * cold + al0 * h0 + al1 * h1;
    m = mn;
    e0 = ep0; e1 = ep1; h0 = hp0; h1 = hp1;
  }

  if (lane < 40){
    float o = acc / fmaxf(denom, 1e-30f) + bias[lane];
    out[(size_t)w * 40 + lane] = o;
  }
}

// ---------------- driver -----------------------------------------------------------

extern "C" void kernel_launch(void* const* d_in, const int* in_sizes, int n_in,
                              void* d_out, int out_size, void* d_ws, size_t ws_size,
                              hipStream_t stream){
  const float* x   = (const float*)d_in[0];
  const int*   ei  = (const int*)d_in[1];
  const float* W1  = (const float*)d_in[2];
  const float* as1 = (const float*)d_in[3];
  const float* ad1 = (const float*)d_in[4];
  const float* b1  = (const float*)d_in[5];
  const float* W2  = (const float*)d_in[6];
  const float* as2 = (const float*)d_in[7];
  const float* ad2 = (const float*)d_in[8];
  const float* b2  = (const float*)d_in[9];
  const float* W3  = (const float*)d_in[10];
  const float* as3 = (const float*)d_in[11];
  const float* ad3 = (const float*)d_in[12];
  const float* b3  = (const float*)d_in[13];

  const int E = in_sizes[1] / 2;             // 800000
  const int ETOT = E + NN;
  const int* src_arr = ei;
  const int* dst_arr = ei + E;

  char* ws = (char*)d_ws;
  size_t off = 0;
  auto alloc = [&](size_t bytes) -> void* {
    void* p = ws + off; off += (bytes + 255) & ~(size_t)255; return p;
  };
  int*   cnt     = (int*)  alloc((size_t)NN * 4);
  int*   row_ptr = (int*)  alloc((size_t)(NN + 1) * 4);
  int*   cursor  = (int*)  alloc((size_t)NN * 4);
  int*   csr     = (int*)  alloc((size_t)ETOT * 4);
  f16*   W1t     = (f16*)  alloc((size_t)512 * 256 * 2);
  f16*   W2t     = (f16*)  alloc((size_t)256 * 256 * 2);
  f16*   W3t     = (f16*)  alloc((size_t)256 * 40 * 2);
  float* a_s     = (float*)alloc((size_t)NN * 4 * 4);
  float* a_d     = (float*)alloc((size_t)NN * 4 * 4);
  f16*   hbuf    = (f16*)  alloc((size_t)NN * 256 * 2);   // fp16 h (per-layer)
  f16*   xbuf    = (f16*)  alloc((size_t)NN * 256 * 2);   // fp16 inter-layer activations
  (void)ws_size; (void)n_in; (void)out_size;

  // CSR build (same graph reused by all 3 layers)
  hipMemsetAsync(cnt, 0, (size_t)NN * 4, stream);
  int egrid = (ETOT + 255) / 256;
  count_k  <<<egrid, 256, 0, stream>>>(dst_arr, cnt, E);
  scan_k   <<<1, 1024, 0, stream>>>(cnt, row_ptr, cursor);
  scatter_k<<<egrid, 256, 0, stream>>>(src_arr, dst_arr, cursor, csr, E);

  // weight transposes (fp32 -> fp16)
  transpose_k<<<(512 * 256 + 255) / 256, 256, 0, stream>>>(W1, W1t, 512, 256);
  transpose_k<<<(256 * 256 + 255) / 256, 256, 0, stream>>>(W2, W2t, 256, 256);
  transpose_k<<<(256 * 40  + 255) / 256, 256, 0, stream>>>(W3, W3t, 256, 40);

  dim3 blk(256);
  dim3 gW((NN + 63) / 64);                   // wide GEMM: full N=256 per block
  dim3 gC((NN + 63) / 64, 1);                // narrow GEMM layer 3 (N=40)
  int nodeblocks = (NN + 3) / 4;             // 12500, one wave per node

  // Layer 1: A = x (fp32), K=512
  gemm_wide_k<true> <<<gW, blk, 0, stream>>>(x, W1t, hbuf, NN, 512);
  attn4_k<<<nodeblocks, blk, 0, stream>>>(hbuf, as1, ad1, a_s, a_d);
  agg4_k <<<nodeblocks, blk, 0, stream>>>(hbuf, a_s, a_d, row_ptr, csr, b1, xbuf);

  // Layer 2: A = xbuf (fp16), K=256
  gemm_wide_k<false><<<gW, blk, 0, stream>>>(xbuf, W2t, hbuf, NN, 256);
  attn4_k<<<nodeblocks, blk, 0, stream>>>(hbuf, as2, ad2, a_s, a_d);
  agg4_k <<<nodeblocks, blk, 0, stream>>>(hbuf, a_s, a_d, row_ptr, csr, b2, xbuf);

  // Layer 3 (H=1, C=40) -> d_out (fp32)
  gemm_k<<<gC, blk, 0, stream>>>(xbuf, W3t, hbuf, NN, 40, 256);
  attn1_k<<<nodeblocks, blk, 0, stream>>>(hbuf, as3, ad3, a_s, a_d);
  agg1_k <<<nodeblocks, blk, 0, stream>>>(hbuf, a_s, a_d, row_ptr, csr, b3, (float*)d_out);
}

// Round 6
// 591.966 us; speedup vs baseline: 1.5830x; 1.1923x over previous
//
#include <hip/hip_runtime.h>
#include <stdint.h>

#define NN 50000   // N_NODES (fixed in reference)
#define NB 196     // ceil(NN/256) scan blocks

typedef unsigned short u16;
typedef _Float16 f16;
typedef __attribute__((ext_vector_type(8))) _Float16 half8;   // MFMA A/B fragment (4 VGPRs)
typedef __attribute__((ext_vector_type(4))) _Float16 half4;
typedef __attribute__((ext_vector_type(4))) float f32x4;

// ---------------- CSR build (dst-sorted adjacency incl. self-loops) ----------------

__global__ void count_k(const int* __restrict__ dst, int* __restrict__ cnt, int E){
  int i = blockIdx.x * 256 + threadIdx.x;
  int tot = E + NN;
  if (i >= tot) return;
  int d = (i < E) ? dst[i] : (i - E);        // self-loop edges appended
  atomicAdd(&cnt[d], 1);
}

// parallel scan, stage 1: per-block (256-wide) sums of cnt
__global__ __launch_bounds__(256) void scan_part_k(const int* __restrict__ cnt,
                                                   int* __restrict__ bsum){
  __shared__ int lds[256];
  int tid = threadIdx.x;
  int idx = blockIdx.x * 256 + tid;
  lds[tid] = (idx < NN) ? cnt[idx] : 0;
  __syncthreads();
#pragma unroll
  for (int off = 128; off >= 1; off >>= 1){
    if (tid < off) lds[tid] += lds[tid + off];
    __syncthreads();
  }
  if (tid == 0) bsum[blockIdx.x] = lds[0];
}

// stage 2: single small block scans the 196 block sums -> exclusive offsets
__global__ __launch_bounds__(256) void scan_top_k(const int* __restrict__ bsum,
                                                  int* __restrict__ boff,
                                                  int* __restrict__ row_ptr){
  __shared__ int lds[256];
  int tid = threadIdx.x;
  int v = (tid < NB) ? bsum[tid] : 0;
  lds[tid] = v;
  __syncthreads();
#pragma unroll
  for (int off = 1; off < 256; off <<= 1){
    int t = (tid >= off) ? lds[tid - off] : 0;
    __syncthreads();
    lds[tid] += t;
    __syncthreads();
  }
  if (tid < NB) boff[tid] = lds[tid] - v;    // exclusive
  if (tid == 255) row_ptr[NN] = lds[255];    // grand total
}

// stage 3: per-block exclusive scan + global offset -> row_ptr / cursor
__global__ __launch_bounds__(256) void scan_fin_k(const int* __restrict__ cnt,
                                                  const int* __restrict__ boff,
                                                  int* __restrict__ row_ptr,
                                                  int* __restrict__ cursor){
  __shared__ int lds[256];
  int tid = threadIdx.x;
  int idx = blockIdx.x * 256 + tid;
  int v = (idx < NN) ? cnt[idx] : 0;
  lds[tid] = v;
  __syncthreads();
#pragma unroll
  for (int off = 1; off < 256; off <<= 1){
    int t = (tid >= off) ? lds[tid - off] : 0;
    __syncthreads();
    lds[tid] += t;
    __syncthreads();
  }
  if (idx < NN){
    int r = boff[blockIdx.x] + lds[tid] - v; // exclusive prefix
    row_ptr[idx] = r;
    cursor[idx]  = r;
  }
}

__global__ void scatter_k(const int* __restrict__ src, const int* __restrict__ dst,
                          int* __restrict__ cursor, int* __restrict__ csr, int E){
  int i = blockIdx.x * 256 + threadIdx.x;
  int tot = E + NN;
  if (i >= tot) return;
  int s, d;
  if (i < E){ s = src[i]; d = dst[i]; } else { s = i - E; d = i - E; }
  int pos = atomicAdd(&cursor[d], 1);
  csr[pos] = s;
}

// -------- W transpose+convert: fp32 [K,N] -> fp16 [N,K] (GEMM B-frags contiguous) ---

__global__ void transpose_k(const float* __restrict__ W, f16* __restrict__ Wt, int K, int N){
  int i = blockIdx.x * 256 + threadIdx.x;
  if (i >= K * N) return;
  int n = i / K, k = i - n * K;
  Wt[i] = (f16)W[k * N + n];                 // write coalesced
}

// ---- wide GEMM: C[M,256](fp16) = A[M,K] * B[K,256]; Bt fp16 [256,K]; A fp32|fp16 ---
// 64x256 block tile: A fetched ONCE (grid-y=1), 4 waves x 16 rows x 16 n-tiles.

template<bool A_FP32>
__global__ __launch_bounds__(256) void gemm_wide_k(const void* __restrict__ Aptr,
                                                   const f16* __restrict__ Bt,
                                                   f16* __restrict__ C,
                                                   int M, int K){
  __shared__ f16 As[64 * 40];                // stride 40 f16 = 80 B: 2-way conflicts (free)
  __shared__ f16 Bs[256 * 40];
  const int tid  = threadIdx.x;
  const int wave = tid >> 6, lane = tid & 63;
  const int quad = lane >> 4, l16 = lane & 15;
  const int m0 = blockIdx.x * 64;
  const int srow = tid >> 2;                 // 64 rows x (4 threads x 8 elems)
  const int scol = (tid & 3) * 8;

  f32x4 acc[16] = {};

  for (int k0 = 0; k0 < K; k0 += 32){
    // stage A (64 x 32)
    half8 va = {0,0,0,0,0,0,0,0};
    int gm = m0 + srow;
    if (gm < M){
      if (A_FP32){
        const float* A = (const float*)Aptr;
        const f32x4 f0 = *(const f32x4*)(A + (size_t)gm * K + k0 + scol);
        const f32x4 f1 = *(const f32x4*)(A + (size_t)gm * K + k0 + scol + 4);
        va[0] = (f16)f0.x; va[1] = (f16)f0.y; va[2] = (f16)f0.z; va[3] = (f16)f0.w;
        va[4] = (f16)f1.x; va[5] = (f16)f1.y; va[6] = (f16)f1.z; va[7] = (f16)f1.w;
      } else {
        va = *(const half8*)((const f16*)Aptr + (size_t)gm * K + k0 + scol);
      }
    }
    *(half8*)(&As[srow * 40 + scol]) = va;

    // stage B (256 x 32), same (row, 8-col) pattern -> 2-way conflicts only
#pragma unroll
    for (int rep = 0; rep < 4; rep++){
      int row = srow + 64 * rep;
      half8 vb = *(const half8*)(Bt + (size_t)row * K + k0 + scol);
      *(half8*)(&Bs[row * 40 + scol]) = vb;
    }

    __syncthreads();
    half8 af = *(const half8*)(&As[(wave * 16 + l16) * 40 + quad * 8]);
#pragma unroll
    for (int i = 0; i < 16; i++){
      half8 bf = *(const half8*)(&Bs[(i * 16 + l16) * 40 + quad * 8]);
      acc[i] = __builtin_amdgcn_mfma_f32_16x16x32_f16(af, bf, acc[i], 0, 0, 0);
    }
    __syncthreads();
  }

#pragma unroll
  for (int i = 0; i < 16; i++){
    int n = i * 16 + l16;
#pragma unroll
    for (int r = 0; r < 4; r++){
      int mm = m0 + wave * 16 + quad * 4 + r; // C/D: col=lane&15, row=quad*4+reg
      if (mm < M) C[(size_t)mm * 256 + n] = (f16)acc[i][r];
    }
  }
}

// ---- narrow GEMM (layer 3): C[M,N](fp16) = A[M,K]*B[K,N], 64x64 tile, A fp16 ------

__global__ __launch_bounds__(256) void gemm_k(const f16* __restrict__ A,
                                              const f16* __restrict__ Bt,
                                              f16* __restrict__ C,
                                              int M, int N, int K){
  __shared__ f16 As[64 * 40];
  __shared__ f16 Bs[64 * 40];
  const int tid  = threadIdx.x;
  const int wave = tid >> 6, lane = tid & 63;
  const int quad = lane >> 4, l16 = lane & 15;
  const int m0 = blockIdx.x * 64, n0 = blockIdx.y * 64;
  const int srow = tid >> 2;
  const int scol = (tid & 3) * 8;

  f32x4 acc[4] = {};

  for (int k0 = 0; k0 < K; k0 += 32){
    half8 va = {0,0,0,0,0,0,0,0};
    int gm = m0 + srow;
    if (gm < M) va = *(const half8*)(A + (size_t)gm * K + k0 + scol);
    *(half8*)(&As[srow * 40 + scol]) = va;

    half8 vb = {0,0,0,0,0,0,0,0};
    int gn = n0 + srow;
    if (gn < N) vb = *(const half8*)(Bt + (size_t)gn * K + k0 + scol);
    *(half8*)(&Bs[srow * 40 + scol]) = vb;

    __syncthreads();
    half8 af = *(const half8*)(&As[(wave * 16 + l16) * 40 + quad * 8]);
#pragma unroll
    for (int i = 0; i < 4; i++){
      half8 bf = *(const half8*)(&Bs[(i * 16 + l16) * 40 + quad * 8]);
      acc[i] = __builtin_amdgcn_mfma_f32_16x16x32_f16(af, bf, acc[i], 0, 0, 0);
    }
    __syncthreads();
  }

#pragma unroll
  for (int i = 0; i < 4; i++){
    int n = n0 + i * 16 + l16;
#pragma unroll
    for (int r = 0; r < 4; r++){
      int m = m0 + wave * 16 + quad * 4 + r;
      if (m < M && n < N) C[(size_t)m * N + n] = (f16)acc[i][r];
    }
  }
}

// ---------------- attention coefficients (h fp16, att vectors fp32) ----------------

// H=4, C=64: one wave per node; lane owns channels 4l..4l+3 (head = l>>4)
__global__ __launch_bounds__(256) void attn4_k(const f16* __restrict__ h,
                                               const float* __restrict__ atts,
                                               const float* __restrict__ attd,
                                               float* __restrict__ a_s,
                                               float* __restrict__ a_d){
  int w = blockIdx.x * 4 + (threadIdx.x >> 6);
  if (w >= NN) return;
  int lane = threadIdx.x & 63;
  const half4 hv = *(const half4*)(h + (size_t)w * 256 + lane * 4);
  const f32x4 sv = *(const f32x4*)(atts + lane * 4);
  const f32x4 dv = *(const f32x4*)(attd + lane * 4);
  float h0 = (float)hv.x, h1 = (float)hv.y, h2 = (float)hv.z, h3 = (float)hv.w;
  float ps = h0 * sv.x + h1 * sv.y + h2 * sv.z + h3 * sv.w;
  float pd = h0 * dv.x + h1 * dv.y + h2 * dv.z + h3 * dv.w;
#pragma unroll
  for (int off = 8; off >= 1; off >>= 1){    // reduce within 16-lane head group
    ps += __shfl_xor(ps, off);
    pd += __shfl_xor(pd, off);
  }
  if ((lane & 15) == 0){
    a_s[w * 4 + (lane >> 4)] = ps;
    a_d[w * 4 + (lane >> 4)] = pd;
  }
}

// H=1, C=40
__global__ __launch_bounds__(256) void attn1_k(const f16* __restrict__ h,
                                               const float* __restrict__ atts,
                                               const float* __restrict__ attd,
                                               float* __restrict__ a_s,
                                               float* __restrict__ a_d){
  int w = blockIdx.x * 4 + (threadIdx.x >> 6);
  if (w >= NN) return;
  int lane = threadIdx.x & 63;
  float ps = 0.f, pd = 0.f;
  if (lane < 40){
    float hv = (float)h[(size_t)w * 40 + lane];
    ps = hv * atts[lane];
    pd = hv * attd[lane];
  }
#pragma unroll
  for (int off = 32; off >= 1; off >>= 1){
    ps += __shfl_xor(ps, off);
    pd += __shfl_xor(pd, off);
  }
  if (lane == 0){ a_s[w] = ps; a_d[w] = pd; }
}

// ---- edge softmax + aggregate: PAIRWISE online softmax, 2-deep prefetch -----------

__device__ __forceinline__ float lrelu(float e){ return e > 0.f ? e : 0.2f * e; }

// H=4, C=64 -> out[N,256](fp16) = ELU(softmax-agg + bias), feeds next GEMM
__global__ __launch_bounds__(256) void agg4_k(const f16* __restrict__ h,
                                              const float* __restrict__ a_s,
                                              const float* __restrict__ a_d,
                                              const int* __restrict__ row_ptr,
                                              const int* __restrict__ csr,
                                              const float* __restrict__ bias,
                                              f16* __restrict__ out){
  int w = blockIdx.x * 4 + (threadIdx.x >> 6);
  if (w >= NN) return;
  int lane = threadIdx.x & 63;
  int head = lane >> 4;
  float ad = a_d[w * 4 + head];
  int beg = row_ptr[w], end = row_ptr[w + 1];

  float m = -1e30f, denom = 0.f;
  float acc0 = 0.f, acc1 = 0.f, acc2 = 0.f, acc3 = 0.f;

  // preload first pair (clamped)
  int s0 = csr[beg];
  int s1 = csr[(beg + 1 < end) ? beg + 1 : beg];
  float e0 = a_s[s0 * 4 + head];
  float e1 = a_s[s1 * 4 + head];
  half4 h0 = *(const half4*)(h + (size_t)s0 * 256 + lane * 4);
  half4 h1 = *(const half4*)(h + (size_t)s1 * 256 + lane * 4);

  for (int j = beg; j < end; j += 2){
    // prefetch next pair (clamped to already-covered indices at the tail)
    int t0 = (j + 2 < end) ? j + 2 : j;
    int t1 = (j + 3 < end) ? j + 3 : j;
    int sp0 = csr[t0], sp1 = csr[t1];
    float ep0 = a_s[sp0 * 4 + head];
    float ep1 = a_s[sp1 * 4 + head];
    half4 hp0 = *(const half4*)(h + (size_t)sp0 * 256 + lane * 4);
    half4 hp1 = *(const half4*)(h + (size_t)sp1 * 256 + lane * 4);

    float ee0 = lrelu(e0 + ad);
    float ee1 = (j + 1 < end) ? lrelu(e1 + ad) : -1e30f;   // mask odd tail
    float mn = fmaxf(m, fmaxf(ee0, ee1));
    float cold = __expf(m - mn);                            // first iter: 0
    float al0 = __expf(ee0 - mn);
    float al1 = __expf(ee1 - mn);                           // masked -> 0
    denom = denom * cold + al0 + al1;
    acc0 = acc0 * cold + al0 * (float)h0.x + al1 * (float)h1.x;
    acc1 = acc1 * cold + al0 * (float)h0.y + al1 * (float)h1.y;
    acc2 = acc2 * cold + al0 * (float)h0.z + al1 * (float)h1.z;
    acc3 = acc3 * cold + al0 * (float)h0.w + al1 * (float)h1.w;
    m = mn;
    e0 = ep0; e1 = ep1; h0 = hp0; h1 = hp1;
  }

  float inv = 1.f / fmaxf(denom, 1e-30f);    // >=1 edge guaranteed (self-loop)
  float o0 = acc0 * inv + bias[lane * 4 + 0];
  float o1 = acc1 * inv + bias[lane * 4 + 1];
  float o2 = acc2 * inv + bias[lane * 4 + 2];
  float o3 = acc3 * inv + bias[lane * 4 + 3];
  o0 = o0 > 0.f ? o0 : __expf(o0) - 1.f;     // ELU
  o1 = o1 > 0.f ? o1 : __expf(o1) - 1.f;
  o2 = o2 > 0.f ? o2 : __expf(o2) - 1.f;
  o3 = o3 > 0.f ? o3 : __expf(o3) - 1.f;
  half4 r; r.x = (f16)o0; r.y = (f16)o1; r.z = (f16)o2; r.w = (f16)o3;
  *(half4*)(out + (size_t)w * 256 + lane * 4) = r;
}

// H=1, C=40 -> out[N,40](fp32) -> d_out, no ELU
__global__ __launch_bounds__(256) void agg1_k(const f16* __restrict__ h,
                                              const float* __restrict__ a_s,
                                              const float* __restrict__ a_d,
                                              const int* __restrict__ row_ptr,
                                              const int* __restrict__ csr,
                                              const float* __restrict__ bias,
                                              float* __restrict__ out){
  int w = blockIdx.x * 4 + (threadIdx.x >> 6);
  if (w >= NN) return;
  int lane = threadIdx.x & 63;
  int cl = (lane < 40) ? lane : 0;
  float ad = a_d[w];
  int beg = row_ptr[w], end = row_ptr[w + 1];

  float m = -1e30f, denom = 0.f, acc = 0.f;

  int s0 = csr[beg];
  int s1 = csr[(beg + 1 < end) ? beg + 1 : beg];
  float e0 = a_s[s0];
  float e1 = a_s[s1];
  float h0 = (float)h[(size_t)s0 * 40 + cl];
  float h1 = (float)h[(size_t)s1 * 40 + cl];

  for (int j = beg; j < end; j += 2){
    int t0 = (j + 2 < end) ? j + 2 : j;
    int t1 = (j + 3 < end) ? j + 3 : j;
    int sp0 = csr[t0], sp1 = csr[t1];
    float ep0 = a_s[sp0];
    float ep1 = a_s[sp1];
    float hp0 = (float)h[(size_t)sp0 * 40 + cl];
    float hp1 = (float)h[(size_t)sp1 * 40 + cl];

    float ee0 = lrelu(e0 + ad);
    float ee1 = (j + 1 < end) ? lrelu(e1 + ad) : -1e30f;
    float mn = fmaxf(m, fmaxf(ee0, ee1));
    float cold = __expf(m - mn);
    float al0 = __expf(ee0 - mn);
    float al1 = __expf(ee1 - mn);
    denom = denom * cold + al0 + al1;
    acc = acc * cold + al0 * h0 + al1 * h1;
    m = mn;
    e0 = ep0; e1 = ep1; h0 = hp0; h1 = hp1;
  }

  if (lane < 40){
    float o = acc / fmaxf(denom, 1e-30f) + bias[lane];
    out[(size_t)w * 40 + lane] = o;
  }
}

// ---------------- driver -----------------------------------------------------------

extern "C" void kernel_launch(void* const* d_in, const int* in_sizes, int n_in,
                              void* d_out, int out_size, void* d_ws, size_t ws_size,
                              hipStream_t stream){
  const float* x   = (const float*)d_in[0];
  const int*   ei  = (const int*)d_in[1];
  const float* W1  = (const float*)d_in[2];
  const float* as1 = (const float*)d_in[3];
  const float* ad1 = (const float*)d_in[4];
  const float* b1  = (const float*)d_in[5];
  const float* W2  = (const float*)d_in[6];
  const float* as2 = (const float*)d_in[7];
  const float* ad2 = (const float*)d_in[8];
  const float* b2  = (const float*)d_in[9];
  const float* W3  = (const float*)d_in[10];
  const float* as3 = (const float*)d_in[11];
  const float* ad3 = (const float*)d_in[12];
  const float* b3  = (const float*)d_in[13];

  const int E = in_sizes[1] / 2;             // 800000
  const int ETOT = E + NN;
  const int* src_arr = ei;
  const int* dst_arr = ei + E;

  char* ws = (char*)d_ws;
  size_t off = 0;
  auto alloc = [&](size_t bytes) -> void* {
    void* p = ws + off; off += (bytes + 255) & ~(size_t)255; return p;
  };
  int*   cnt     = (int*)  alloc((size_t)NN * 4);
  int*   row_ptr = (int*)  alloc((size_t)(NN + 1) * 4);
  int*   cursor  = (int*)  alloc((size_t)NN * 4);
  int*   csr     = (int*)  alloc((size_t)ETOT * 4);
  int*   bsum    = (int*)  alloc((size_t)256 * 4);
  int*   boff    = (int*)  alloc((size_t)256 * 4);
  f16*   W1t     = (f16*)  alloc((size_t)512 * 256 * 2);
  f16*   W2t     = (f16*)  alloc((size_t)256 * 256 * 2);
  f16*   W3t     = (f16*)  alloc((size_t)256 * 40 * 2);
  float* a_s     = (float*)alloc((size_t)NN * 4 * 4);
  float* a_d     = (float*)alloc((size_t)NN * 4 * 4);
  f16*   hbuf    = (f16*)  alloc((size_t)NN * 256 * 2);   // fp16 h (per-layer)
  f16*   xbuf    = (f16*)  alloc((size_t)NN * 256 * 2);   // fp16 inter-layer activations
  (void)ws_size; (void)n_in; (void)out_size;

  // CSR build (same graph reused by all 3 layers)
  hipMemsetAsync(cnt, 0, (size_t)NN * 4, stream);
  int egrid = (ETOT + 255) / 256;
  count_k    <<<egrid, 256, 0, stream>>>(dst_arr, cnt, E);
  scan_part_k<<<NB, 256, 0, stream>>>(cnt, bsum);
  scan_top_k <<<1, 256, 0, stream>>>(bsum, boff, row_ptr);
  scan_fin_k <<<NB, 256, 0, stream>>>(cnt, boff, row_ptr, cursor);
  scatter_k  <<<egrid, 256, 0, stream>>>(src_arr, dst_arr, cursor, csr, E);

  // weight transposes (fp32 -> fp16)
  transpose_k<<<(512 * 256 + 255) / 256, 256, 0, stream>>>(W1, W1t, 512, 256);
  transpose_k<<<(256 * 256 + 255) / 256, 256, 0, stream>>>(W2, W2t, 256, 256);
  transpose_k<<<(256 * 40  + 255) / 256, 256, 0, stream>>>(W3, W3t, 256, 40);

  dim3 blk(256);
  dim3 gW((NN + 63) / 64);                   // wide GEMM: full N=256 per block
  dim3 gC((NN + 63) / 64, 1);                // narrow GEMM layer 3 (N=40)
  int nodeblocks = (NN + 3) / 4;             // 12500, one wave per node

  // Layer 1: A = x (fp32), K=512
  gemm_wide_k<true> <<<gW, blk, 0, stream>>>(x, W1t, hbuf, NN, 512);
  attn4_k<<<nodeblocks, blk, 0, stream>>>(hbuf, as1, ad1, a_s, a_d);
  agg4_k <<<nodeblocks, blk, 0, stream>>>(hbuf, a_s, a_d, row_ptr, csr, b1, xbuf);

  // Layer 2: A = xbuf (fp16), K=256
  gemm_wide_k<false><<<gW, blk, 0, stream>>>(xbuf, W2t, hbuf, NN, 256);
  attn4_k<<<nodeblocks, blk, 0, stream>>>(hbuf, as2, ad2, a_s, a_d);
  agg4_k <<<nodeblocks, blk, 0, stream>>>(hbuf, a_s, a_d, row_ptr, csr, b2, xbuf);

  // Layer 3 (H=1, C=40) -> d_out (fp32)
  gemm_k<<<gC, blk, 0, stream>>>(xbuf, W3t, hbuf, NN, 40, 256);
  attn1_k<<<nodeblocks, blk, 0, stream>>>(hbuf, as3, ad3, a_s, a_d);
  agg1_k <<<nodeblocks, blk, 0, stream>>>(hbuf, a_s, a_d, row_ptr, csr, b3, (float*)d_out);
}